// Round 8
// baseline (36.169 us; speedup 1.0000x reference)
//
#include <hip/hip_runtime.h>

#define NB 64
#define NC 206
#define N (NB * NC)        // 13184
#define IPT 4              // positives per thread
#define GX 13              // ceil(N / 1024) worst-case positive coverage
#define GY 64              // group-chunk splits
#define NBLK (GX * GY)     // 832
#define MAXG 3328          // worst-case groups: 64 * ceil(206/4)
#define MAXCHUNK 52        // ceil(MAXG / GY)
#define LN2F 0.69314718056f

// Workspace. Poisoned once to 0xAA; prep rewrites every field read later,
// and zeroes acc/done each call (required for graph replay determinism).
struct Ws {
    float2 pos[N];            // compacted positives {exp(-p), w}
    float  EG[MAXG * 4];      // grouped negative exp(p), zero-padded to 4
    float  WG[MAXG];          // per-group weight * ln2
    unsigned int npos, nneg, ngroups, done;
    double acc;
};

// ---- single-block deterministic prep: compact + transform + group ----
__global__ __launch_bounds__(1024) void prep_kernel(
    const float* __restrict__ preds,
    const float* __restrict__ sw,
    const int* __restrict__ labels,
    Ws* __restrict__ ws)
{
    const int wave = threadIdx.x >> 6;   // 0..15
    const int lane = threadIdx.x & 63;

    __shared__ int rowPos[NB], rowNeg[NB];
    __shared__ int posBase[NB], grpBase[NB];
    __shared__ unsigned int totals[3];   // npos, nneg, ngroups

    // phase 1: per-row counts (wave w owns rows w, w+16, ...)
    for (int r = wave; r < NB; r += 16) {
        int pc = 0, nc = 0;
        for (int c0 = 0; c0 < NC; c0 += 64) {
            int c = c0 + lane;
            int l = (c < NC) ? labels[r * NC + c] : -1;
            pc += __popcll(__ballot(l == 1));
            nc += __popcll(__ballot(l == 0));
        }
        if (lane == 0) { rowPos[r] = pc; rowNeg[r] = nc; }
    }
    __syncthreads();

    // phase 2: exclusive scans over 64 rows by wave 0
    if (wave == 0) {
        int pc = rowPos[lane];
        int nc = rowNeg[lane];
        int gc = (nc + 3) >> 2;
        int ip = pc, in_ = nc, ig = gc;
        #pragma unroll
        for (int off = 1; off < 64; off <<= 1) {
            int tp = __shfl_up(ip, off, 64);
            int tn = __shfl_up(in_, off, 64);
            int tg = __shfl_up(ig, off, 64);
            if (lane >= off) { ip += tp; in_ += tn; ig += tg; }
        }
        posBase[lane] = ip - pc;
        grpBase[lane] = ig - gc;
        if (lane == 63) { totals[0] = ip; totals[1] = in_; totals[2] = ig; }
    }
    __syncthreads();
    if (threadIdx.x == 0) {
        ws->npos    = totals[0];
        ws->nneg    = totals[1];
        ws->ngroups = totals[2];
        ws->done    = 0;          // ticket counter, reset every call
        ws->acc     = 0.0;        // accumulator, reset every call
    }

    // phase 3: ordered compaction writes
    for (int r = wave; r < NB; r += 16) {
        const float w    = sw[r];
        const float wln2 = w * LN2F;
        int pOff = posBase[r];
        int nIdx = 0;
        const int gBase = grpBase[r];
        for (int c0 = 0; c0 < NC; c0 += 64) {
            int c = c0 + lane;
            bool inb = (c < NC);
            float p = inb ? preds[r * NC + c] : 0.0f;
            int   l = inb ? labels[r * NC + c] : -1;
            unsigned long long balP = __ballot(l == 1);
            unsigned long long balN = __ballot(l == 0);
            unsigned long long pre  = (1ull << lane) - 1ull;
            if (l == 1) {
                int o = pOff + __popcll(balP & pre);
                ws->pos[o] = make_float2(__expf(-p), w);
            }
            if (l == 0) {
                int idx = nIdx + __popcll(balN & pre);
                int g   = gBase + (idx >> 2);
                ws->EG[g * 4 + (idx & 3)] = __expf(p);
                if ((idx & 3) == 0) ws->WG[g] = wln2;
            }
            pOff += __popcll(balP);
            nIdx += __popcll(balN);
        }
        // zero-pad the row's last group (E=0 -> t=1 -> log contribution 0)
        int fill = nIdx & 3;
        if (fill) {
            int gLast = gBase + (nIdx >> 2);
            if (lane < 4 - fill) ws->EG[gLast * 4 + fill + lane] = 0.0f;
        }
    }
}

// ---- pairs + fence-free ticket finalize ----
__global__ __launch_bounds__(256) void pairs_kernel(
    Ws* __restrict__ ws,
    float* __restrict__ out)
{
    const int bid     = blockIdx.y * gridDim.x + blockIdx.x;
    const int npos    = (int)ws->npos;
    const int ngroups = (int)ws->ngroups;
    const int i0      = blockIdx.x * (256 * IPT);
    const int lane    = threadIdx.x & 63;
    const int wid     = threadIdx.x >> 6;

    __shared__ float4 sEG[MAXCHUNK];
    __shared__ float  sWG[MAXCHUNK];
    __shared__ float  wsum[4];

    if (i0 < npos) {                       // block-uniform
        const int per = (ngroups + GY - 1) / GY;
        const int g0  = blockIdx.y * per;
        const int gn  = min(per, ngroups - g0);    // may be <= 0
        for (int t = threadIdx.x; t < gn; t += 256) {
            sEG[t] = *(const float4*)&ws->EG[(g0 + t) * 4];
            sWG[t] = ws->WG[g0 + t];
        }
        __syncthreads();

        float F[IPT], PW[IPT], acc[IPT];
        #pragma unroll
        for (int k = 0; k < IPT; ++k) {
            int i = i0 + k * 256 + threadIdx.x;
            if (i < npos) { float2 s = ws->pos[i]; F[k] = s.x; PW[k] = s.y; }
            else          { F[k] = 0.0f; PW[k] = 0.0f; }   // t=1 -> log=0
            acc[k] = 0.0f;
        }

        // 4 pairs per (group,k): 4 fma + 3 mul + 1 log2 + 1 fma
        #pragma unroll 2
        for (int g = 0; g < gn; ++g) {
            float4 e = sEG[g];             // broadcast ds_read_b128
            float wg = sWG[g];
            #pragma unroll
            for (int k = 0; k < IPT; ++k) {
                float t0 = fmaf(e.x, F[k], 1.0f);
                float t1 = fmaf(e.y, F[k], 1.0f);
                float t2 = fmaf(e.z, F[k], 1.0f);
                float t3 = fmaf(e.w, F[k], 1.0f);
                float m  = (t0 * t1) * (t2 * t3);   // <= ~4e14, no overflow
                acc[k] = fmaf(__log2f(m), wg, acc[k]);
            }
        }

        float a = 0.0f;
        #pragma unroll
        for (int k = 0; k < IPT; ++k) a = fmaf(acc[k], PW[k], a);
        #pragma unroll
        for (int off = 32; off > 0; off >>= 1)
            a += __shfl_down(a, off, 64);
        if (lane == 0) wsum[wid] = a;
        __syncthreads();
    } else {
        if (threadIdx.x < 4) wsum[threadIdx.x] = 0.0f;
        __syncthreads();
    }

    // fence-free finalize: device-scope atomics only, ordered by data dep.
    __shared__ int isLast;
    if (threadIdx.x == 0) {
        double partial = (double)(wsum[0] + wsum[1] + wsum[2] + wsum[3]);
        double old = atomicAdd(&ws->acc, partial);   // committed at coherent point
        asm volatile("" : : "v"(old));               // waitcnt: RMW complete before ticket
        unsigned int t = atomicAdd(&ws->done, 1u);
        isLast = (t == NBLK - 1) ? 1 : 0;
    }
    __syncthreads();

    if (isLast && threadIdx.x == 0) {
        double total = atomicAdd(&ws->acc, 0.0);     // atomic read at coherent point
        double denom = (double)ws->npos * (double)ws->nneg;
        out[0] = (float)(total / denom);
    }
}

extern "C" void kernel_launch(void* const* d_in, const int* in_sizes, int n_in,
                              void* d_out, int out_size, void* d_ws, size_t ws_size,
                              hipStream_t stream)
{
    const float* preds  = (const float*)d_in[0];
    const float* sw     = (const float*)d_in[1];
    const int*   labels = (const int*)d_in[2];
    float* out = (float*)d_out;
    Ws* ws = (Ws*)d_ws;

    prep_kernel<<<1, 1024, 0, stream>>>(preds, sw, labels, ws);

    dim3 grid(GX, GY);
    pairs_kernel<<<grid, 256, 0, stream>>>(ws, out);
}

// Round 9
// 22.547 us; speedup vs baseline: 1.6041x; 1.6041x over previous
//
#include <hip/hip_runtime.h>

#define NB 64
#define NC 206
#define N (NB * NC)        // 13184
#define IPT 4              // i-elements per thread (256 thr -> 1024 i-window)
#define GX 13              // ceil(N / 1024) i-windows
#define NGPR 52            // groups per row = ceil(206/4)
#define NBLK (GX * NB)     // 832 blocks: x = i-window, y = sample row
#define LN2F 0.69314718056f

// Workspace: per-block partials only. All NBLK slots are unconditionally
// rewritten by pairs_kernel every call — no zero-init, no atomics anywhere.
struct Ws {
    double partials[NBLK];
};

// ---- pairs: consume RAW inputs, masking via the grouped-log identity ----
// contribution(i,j) = w_i * w_j * softplus(p_j - p_i)   for i pos, j neg
//   = w_i * (w_j*ln2) * log2(1 + e^{p_j} * e^{-p_i})
// mask j: E_j = 0 unless label_j==0  -> t = 1 -> log2-term 0
// mask i: PW_i = 0 unless label_i==1 -> whole i-contribution 0
// blockIdx.y == sample row => w_j uniform scalar, hoisted out of the loop.
__global__ __launch_bounds__(256) void pairs_kernel(
    const float* __restrict__ preds,
    const float* __restrict__ sw,
    const int* __restrict__ labels,
    double* __restrict__ partials)
{
    const int bx   = blockIdx.x;          // i-window
    const int row  = blockIdx.y;          // j-row
    const int lane = threadIdx.x & 63;
    const int wid  = threadIdx.x >> 6;

    __shared__ float sEGf[NGPR * 4];      // masked exp(p_neg), 0-padded to 208
    __shared__ float wsum[4];

    // stage this row's masked E values (one pass, threads 0..207)
    {
        const int c = threadIdx.x;
        if (c < NGPR * 4) {
            float e = 0.0f;
            if (c < NC) {
                float p = preds[row * NC + c];
                int   l = labels[row * NC + c];
                e = (l == 0) ? __expf(p) : 0.0f;
            }
            sEGf[c] = e;
        }
    }

    // i-side: masked loads straight from raw inputs
    float F[IPT], PW[IPT], acc[IPT];
    #pragma unroll
    for (int k = 0; k < IPT; ++k) {
        int i = bx * 1024 + k * 256 + threadIdx.x;
        if (i < N) {
            float p = preds[i];
            int   l = labels[i];
            F[k]  = __expf(-p);
            PW[k] = (l == 1) ? sw[i / NC] : 0.0f;
        } else {
            F[k] = 0.0f; PW[k] = 0.0f;
        }
        acc[k] = 0.0f;
    }
    __syncthreads();

    const float4* sEG = (const float4*)sEGf;

    // inner: per (group, k) = 4 pairs: 4 fma + 3 mul + 1 log2 + 1 add
    #pragma unroll 2
    for (int g = 0; g < NGPR; ++g) {
        float4 e = sEG[g];                // broadcast ds_read_b128
        #pragma unroll
        for (int k = 0; k < IPT; ++k) {
            float t0 = fmaf(e.x, F[k], 1.0f);
            float t1 = fmaf(e.y, F[k], 1.0f);
            float t2 = fmaf(e.z, F[k], 1.0f);
            float t3 = fmaf(e.w, F[k], 1.0f);
            float m  = (t0 * t1) * (t2 * t3);   // bounded ~1e35 worst-case, no overflow
            acc[k] += __log2f(m);
        }
    }

    // fold per-i weight, then the row's uniform w*ln2
    float a = 0.0f;
    #pragma unroll
    for (int k = 0; k < IPT; ++k) a = fmaf(acc[k], PW[k], a);
    a *= sw[row] * LN2F;

    #pragma unroll
    for (int off = 32; off > 0; off >>= 1)
        a += __shfl_down(a, off, 64);

    if (lane == 0) wsum[wid] = a;
    __syncthreads();
    if (threadIdx.x == 0)
        partials[row * GX + bx] = (double)(wsum[0] + wsum[1] + wsum[2] + wsum[3]);
}

// ---- reduce: sum partials + count labels for the denominator ----
__global__ __launch_bounds__(256) void reduce_kernel(
    const int* __restrict__ labels,
    const Ws* __restrict__ ws,
    float* __restrict__ out)
{
    const int lane = threadIdx.x & 63;
    const int wid  = threadIdx.x >> 6;

    // sum the 832 partials
    double s = 0.0;
    for (int t = threadIdx.x; t < NBLK; t += 256)
        s += ws->partials[t];

    // count positives (labels are 0/1); N = 3296 int4's exactly
    int pc = 0;
    const int4* l4 = (const int4*)labels;
    for (int t = threadIdx.x; t < N / 4; t += 256) {
        int4 v = l4[t];
        pc += v.x + v.y + v.z + v.w;
    }

    #pragma unroll
    for (int off = 32; off > 0; off >>= 1) {
        s  += __shfl_down(s, off, 64);
        pc += __shfl_down(pc, off, 64);
    }

    __shared__ double ds[4];
    __shared__ int    dp[4];
    if (lane == 0) { ds[wid] = s; dp[wid] = pc; }
    __syncthreads();
    if (threadIdx.x == 0) {
        double total = ds[0] + ds[1] + ds[2] + ds[3];
        int npos     = dp[0] + dp[1] + dp[2] + dp[3];
        double denom = (double)npos * (double)(N - npos);
        out[0] = (float)(total / denom);
    }
}

extern "C" void kernel_launch(void* const* d_in, const int* in_sizes, int n_in,
                              void* d_out, int out_size, void* d_ws, size_t ws_size,
                              hipStream_t stream)
{
    const float* preds  = (const float*)d_in[0];
    const float* sw     = (const float*)d_in[1];
    const int*   labels = (const int*)d_in[2];
    float* out = (float*)d_out;
    Ws* ws = (Ws*)d_ws;

    dim3 grid(GX, NB);
    pairs_kernel<<<grid, 256, 0, stream>>>(preds, sw, labels, ws->partials);

    reduce_kernel<<<1, 256, 0, stream>>>(labels, ws, out);
}

// Round 10
// 21.592 us; speedup vs baseline: 1.6751x; 1.0442x over previous
//
#include <hip/hip_runtime.h>

#define NB 64
#define NC 206
#define N (NB * NC)        // 13184
#define GX 13              // ceil(N / 1024) i-windows
#define NG8 26             // 8-wide groups per row = ceil(206/8)
#define NBLK (GX * NB)     // 832 blocks: x = i-window, y = sample row
#define LN2F 0.69314718056f

// Workspace: per-block partials only. All NBLK slots unconditionally
// rewritten every call — no zero-init, no atomics anywhere.
struct Ws {
    double partials[NBLK];
};

// contribution(i,j) = w_i * w_j * softplus(p_j - p_i),  i pos, j neg
//   = w_i * (w_row * ln2) * log2(1 + e^{p_j} * e^{-p_i})
// j masked via E_j = 0 (t=1 -> log-term 0); i compacted in-block.
__global__ __launch_bounds__(256) void pairs_kernel(
    const float* __restrict__ preds,
    const float* __restrict__ sw,
    const int* __restrict__ labels,
    double* __restrict__ partials)
{
    const int bx   = blockIdx.x;          // i-window (1024 raw elements)
    const int row  = blockIdx.y;          // j-row
    const int tid  = threadIdx.x;
    const int lane = tid & 63;
    const int wave = tid >> 6;

    __shared__ float sEGf[NG8 * 8];       // masked exp(p_neg), 0-padded to 208
    __shared__ float sF[1024], sPW[1024]; // compacted positives of this window
    __shared__ int   segCnt[16];          // per (k,wave) active counts
    __shared__ float wsum[4];

    // ---- stage this row's masked E values (threads 0..207) ----
    if (tid < NG8 * 8) {
        float e = 0.0f;
        if (tid < NC) {
            float p = preds[row * NC + tid];
            int   l = labels[row * NC + tid];
            e = (l == 0) ? __expf(p) : 0.0f;
        }
        sEGf[tid] = e;
    }

    // ---- deterministic in-block compaction of positive i's ----
    float pv[4]; float wv[4]; unsigned int rank[4]; bool act[4];
    unsigned long long pre = (1ull << lane) - 1ull;
    #pragma unroll
    for (int k = 0; k < 4; ++k) {
        int i = bx * 1024 + k * 256 + tid;
        bool a = false; float p = 0.0f, w = 0.0f;
        if (i < N) {
            p = preds[i];
            a = (labels[i] == 1);
            if (a) w = sw[i / NC];
        }
        unsigned long long ball = __ballot(a);
        if (lane == 0) segCnt[k * 4 + wave] = __popcll(ball);
        rank[k] = (unsigned int)__popcll(ball & pre);
        act[k] = a; pv[k] = p; wv[k] = w;
    }
    __syncthreads();

    int segBase[4]; int nAct = 0;
    {
        int run = 0;
        #pragma unroll
        for (int s = 0; s < 16; ++s) {
            int c = segCnt[s];                 // broadcast LDS read
            int k = s >> 2, wv_ = s & 3;
            if (wv_ == wave) segBase[k] = run; // base for my (k,wave) segment
            run += c;
        }
        nAct = run;
    }
    #pragma unroll
    for (int k = 0; k < 4; ++k) {
        if (act[k]) {
            int o = segBase[k] + (int)rank[k];
            sF[o]  = __expf(-pv[k]);
            sPW[o] = wv[k];
        }
    }
    __syncthreads();

    // ---- pair loop over compacted i's, 2-way ILP, 8-wide log groups ----
    const float4* sEG4 = (const float4*)sEGf;
    float a = 0.0f;
    for (int base = 0; base < nAct; base += 512) {
        int i0 = base + tid, i1 = base + 256 + tid;
        float F0 = 0.0f, P0 = 0.0f, F1 = 0.0f, P1 = 0.0f;
        if (i0 < nAct) { F0 = sF[i0]; P0 = sPW[i0]; }
        if (i1 < nAct) { F1 = sF[i1]; P1 = sPW[i1]; }
        float a0 = 0.0f, a1 = 0.0f;
        #pragma unroll 2
        for (int g = 0; g < NG8; ++g) {
            float4 e0 = sEG4[2 * g];          // broadcast ds_read_b128
            float4 e1 = sEG4[2 * g + 1];
            float m0, m1;
            {
                float t0 = fmaf(e0.x, F0, 1.0f), t1 = fmaf(e0.y, F0, 1.0f);
                float t2 = fmaf(e0.z, F0, 1.0f), t3 = fmaf(e0.w, F0, 1.0f);
                float t4 = fmaf(e1.x, F0, 1.0f), t5 = fmaf(e1.y, F0, 1.0f);
                float t6 = fmaf(e1.z, F0, 1.0f), t7 = fmaf(e1.w, F0, 1.0f);
                m0 = ((t0 * t1) * (t2 * t3)) * ((t4 * t5) * (t6 * t7));
            }
            {
                float t0 = fmaf(e0.x, F1, 1.0f), t1 = fmaf(e0.y, F1, 1.0f);
                float t2 = fmaf(e0.z, F1, 1.0f), t3 = fmaf(e0.w, F1, 1.0f);
                float t4 = fmaf(e1.x, F1, 1.0f), t5 = fmaf(e1.y, F1, 1.0f);
                float t6 = fmaf(e1.z, F1, 1.0f), t7 = fmaf(e1.w, F1, 1.0f);
                m1 = ((t0 * t1) * (t2 * t3)) * ((t4 * t5) * (t6 * t7));
            }
            a0 += __log2f(m0);               // max product ~1.8e31 < f32 max
            a1 += __log2f(m1);
        }
        a = fmaf(a0, P0, a);
        a = fmaf(a1, P1, a);
    }
    a *= sw[row] * LN2F;

    // ---- block reduce, one global write ----
    #pragma unroll
    for (int off = 32; off > 0; off >>= 1)
        a += __shfl_down(a, off, 64);
    if (lane == 0) wsum[wave] = a;
    __syncthreads();
    if (tid == 0)
        partials[row * GX + bx] = (double)(wsum[0] + wsum[1] + wsum[2] + wsum[3]);
}

// ---- reduce: sum partials + count labels for the denominator ----
__global__ __launch_bounds__(256) void reduce_kernel(
    const int* __restrict__ labels,
    const Ws* __restrict__ ws,
    float* __restrict__ out)
{
    const int lane = threadIdx.x & 63;
    const int wid  = threadIdx.x >> 6;

    double s = 0.0;
    for (int t = threadIdx.x; t < NBLK; t += 256)
        s += ws->partials[t];

    int pc = 0;
    const int4* l4 = (const int4*)labels;
    for (int t = threadIdx.x; t < N / 4; t += 256) {
        int4 v = l4[t];
        pc += v.x + v.y + v.z + v.w;
    }

    #pragma unroll
    for (int off = 32; off > 0; off >>= 1) {
        s  += __shfl_down(s, off, 64);
        pc += __shfl_down(pc, off, 64);
    }

    __shared__ double ds[4];
    __shared__ int    dp[4];
    if (lane == 0) { ds[wid] = s; dp[wid] = pc; }
    __syncthreads();
    if (threadIdx.x == 0) {
        double total = ds[0] + ds[1] + ds[2] + ds[3];
        int npos     = dp[0] + dp[1] + dp[2] + dp[3];
        double denom = (double)npos * (double)(N - npos);
        out[0] = (float)(total / denom);
    }
}

extern "C" void kernel_launch(void* const* d_in, const int* in_sizes, int n_in,
                              void* d_out, int out_size, void* d_ws, size_t ws_size,
                              hipStream_t stream)
{
    const float* preds  = (const float*)d_in[0];
    const float* sw     = (const float*)d_in[1];
    const int*   labels = (const int*)d_in[2];
    float* out = (float*)d_out;
    Ws* ws = (Ws*)d_ws;

    dim3 grid(GX, NB);
    pairs_kernel<<<grid, 256, 0, stream>>>(preds, sw, labels, ws->partials);

    reduce_kernel<<<1, 256, 0, stream>>>(labels, ws, out);
}